// Round 2
// baseline (1720.144 us; speedup 1.0000x reference)
//
#include <hip/hip_runtime.h>
#include <stdint.h>

typedef unsigned short ushort_t;
typedef unsigned int uint_t;

#define H_SZ   1024
#define D_OUT  512
#define MAXN   64
#define MIDSP  512
#define MIDCD  512
#define MIDDEC 768

typedef __bf16 bf16x8 __attribute__((ext_vector_type(8)));
typedef float  f32x4  __attribute__((ext_vector_type(4)));

static __device__ __forceinline__ float asf(uint_t u) { union { uint_t i; float f; } c; c.i = u; return c.f; }
static __device__ __forceinline__ uint_t rnbf(float f) {            // fp32 -> bf16 (RNE), low 16 bits
  union { uint_t i; float f; } c; c.f = f;
  return (c.i + 0x7fffu + ((c.i >> 16) & 1u)) >> 16;
}
static __device__ __forceinline__ ushort_t f2bf(float f) { return (ushort_t)rnbf(f); }
static __device__ __forceinline__ uint_t mul2bf(uint_t a, uint_t b) {  // 2x packed bf16 multiply
  float a0 = asf(a << 16), a1 = asf(a & 0xffff0000u);
  float b0 = asf(b << 16), b1 = asf(b & 0xffff0000u);
  return rnbf(a0 * b0) | (rnbf(a1 * b1) << 16);
}
static __device__ __forceinline__ double mish_d(double x) { return x * tanh(log1p(exp(x))); }
static __device__ __forceinline__ float mish_f(float x) {
  // mish(x) = x*(t^2+2t)/(t^2+2t+2), t=e^x  (algebraic tanh(softplus))
  float t = __expf(x);
  float u = t * t + 2.f * t;
  float r = u / (u + 2.f);
  return (x > 30.f) ? x : x * r;
}

// ---------------- transpose + fp32->bf16 convert (dims multiples of 32) ----------------
__global__ __launch_bounds__(256) void k_transpose_cvt(const float* __restrict__ src,
                                                       ushort_t* __restrict__ dst, int R, int C) {
  __shared__ float tile[32][33];
  const int c0 = blockIdx.x * 32, r0 = blockIdx.y * 32;
  const int tc = threadIdx.x & 31, tr = threadIdx.x >> 5;
#pragma unroll
  for (int i = 0; i < 4; ++i) {
    const int r = tr + i * 8;
    tile[r][tc] = src[(size_t)(r0 + r) * C + (c0 + tc)];
  }
  __syncthreads();
#pragma unroll
  for (int i = 0; i < 4; ++i) {
    const int rr = tr + i * 8;
    dst[(size_t)(c0 + rr) * R + (r0 + tc)] = f2bf(tile[tc][rr]);
  }
}

// ---------------- key table fp32 -> bf16 ----------------
__global__ __launch_bounds__(256) void k_cvtkey(const float* __restrict__ src, ushort_t* __restrict__ dst) {
  const int i = blockIdx.x * 1024 + threadIdx.x;
#pragma unroll
  for (int j = 0; j < 4; ++j) dst[i + j * 256] = f2bf(src[i + j * 256]);
}

// ---------------- enc table: enc[v] = mish(v*cd_w1+cd_b1) @ cd_w2 + cd_b2 ----------------
__global__ __launch_bounds__(256) void k_enc(const float* __restrict__ w1, const float* __restrict__ b1,
                                             const float* __restrict__ w2, const float* __restrict__ b2,
                                             float* __restrict__ enc) {
  const int v = blockIdx.x, t = threadIdx.x;
  __shared__ float m[MIDCD];
  for (int i = t; i < MIDCD; i += 256) {
    double a = (double)v * (double)w1[i] + (double)b1[i];
    m[i] = (float)mish_d(a);
  }
  __syncthreads();
  for (int c = t; c < H_SZ; c += 256) {
    double s = (double)b2[c];
    for (int k = 0; k < MIDCD; ++k) s += (double)m[k] * (double)w2[(size_t)k * H_SZ + c];
    enc[(size_t)v * H_SZ + c] = (float)s;
  }
}

// ---------------- n-path: 8 rows per block; fp32 S accumulation, fp64 LN/mish/dot ----------------
__global__ __launch_bounds__(256) void k_npath(
    const float* __restrict__ z, const float* __restrict__ w1, const float* __restrict__ b1,
    const float* __restrict__ g, const float* __restrict__ be,
    const float* __restrict__ w2, const float* __restrict__ b2,
    const float* __restrict__ enc, int* __restrict__ nbuf,
    ushort_t* __restrict__ zc, float* __restrict__ outb) {
  const int t = threadIdx.x;
  const int r0 = blockIdx.x * 8;
  const int lane = t & 63, wv = t >> 6;
  __shared__ float zs[8][H_SZ];      // 32 KB
  __shared__ double wred[4];
  __shared__ int n8[8];

#pragma unroll
  for (int i = 0; i < 32; ++i) {
    const int idx = i * 256 + t;
    zs[idx >> 10][idx & 1023] = z[(size_t)r0 * H_SZ + idx];
  }
  __syncthreads();

  const int c0 = t, c1 = t + 256;
  float a0[8], a1[8];
#pragma unroll
  for (int r = 0; r < 8; ++r) { a0[r] = 0.f; a1[r] = 0.f; }

  for (int k = 0; k < H_SZ; k += 4) {
    float4 zr[8];
#pragma unroll
    for (int r = 0; r < 8; ++r) zr[r] = *(const float4*)&zs[r][k];
#pragma unroll
    for (int kk = 0; kk < 4; ++kk) {
      const float w0 = w1[(size_t)(k + kk) * MIDSP + c0];
      const float w1v = w1[(size_t)(k + kk) * MIDSP + c1];
#pragma unroll
      for (int r = 0; r < 8; ++r) {
        const float zk = ((const float*)&zr[r])[kk];
        a0[r] += zk * w0;
        a1[r] += zk * w1v;
      }
    }
  }

  auto block_sum = [&](double v) -> double {
#pragma unroll
    for (int off = 32; off > 0; off >>= 1) v += __shfl_down(v, off, 64);
    if (lane == 0) wred[wv] = v;
    __syncthreads();
    const double s = wred[0] + wred[1] + wred[2] + wred[3];
    __syncthreads();
    return s;
  };

  const double bia0 = (double)b1[c0], bia1 = (double)b1[c1];
  const double g0 = (double)g[c0], g1 = (double)g[c1];
  const double be0 = (double)be[c0], be1 = (double)be[c1];
  const double wv0 = (double)w2[c0], wv1 = (double)w2[c1];
  const double b2v = (double)b2[0];

  for (int r = 0; r < 8; ++r) {
    const double x0 = (double)a0[r] + bia0;
    const double x1 = (double)a1[r] + bia1;
    const double mu = block_sum(x0 + x1) * (1.0 / 512.0);
    const double varr = block_sum((x0 - mu) * (x0 - mu) + (x1 - mu) * (x1 - mu)) * (1.0 / 512.0);
    const double rs = 1.0 / sqrt(varr + 1e-5);
    const double h0 = mish_d((x0 - mu) * rs * g0 + be0);
    const double h1 = mish_d((x1 - mu) * rs * g1 + be1);
    const double logit = block_sum(h0 * wv0 + h1 * wv1) + b2v;
    if (t == 0) n8[r] = (int)fmin(64.0, fmax(0.0, rint(logit)));  // rint = half-to-even = np.round
  }
  __syncthreads();

  if (t < 8) nbuf[r0 + t] = n8[t];
#pragma unroll
  for (int i = 0; i < 2; ++i) {
    const int idx = i * 256 + t;
    const int r = idx >> 6, j = idx & 63;
    outb[(size_t)(r0 + r) * MAXN + j] = (j < n8[r]) ? (float)(r0 + r) : -1.0f;
  }
#pragma unroll
  for (int i = 0; i < 32; ++i) {
    const int idx = i * 256 + t;
    const int r = idx >> 10, c = idx & 1023;
    zc[(size_t)(r0 + r) * H_SZ + c] = f2bf(zs[r][c] - enc[(size_t)n8[r] * H_SZ + c]);
  }
}

// ---------------- fused decoder v3: 32 rows per block (2 blocks per b) ----------------
// Accumulator footprint halved vs v2 so 2 blocks/CU fit WITHOUT spills:
//   acc2[2][4]=32 + acc[2][2]=16 regs; peak live ~110 <= 128 (4 waves/SIMD budget).
// sA: double-buffered 32x128-K A stages, row stride 256B, XOR-16B-chunk swizzle -> 16 KB
// sT: 32 x 256-col bf16 slab, row stride 512B, XOR swizzle                      -> 16 KB
// K-stage = 128 (was 64): halves barrier count (8 s-steps/pass).
// Blocks with no live rows (n <= half*32) zero-fill their 32x512 output and exit.
__global__ __launch_bounds__(512, 4) void k_dec(
    const ushort_t* __restrict__ key, const ushort_t* __restrict__ w1t,
    const float* __restrict__ db1, const ushort_t* __restrict__ w2t,
    const float* __restrict__ db2, const ushort_t* __restrict__ zc,
    const int* __restrict__ nbuf, float* __restrict__ out) {
  __shared__ char sA[16384];       // 2 x (32 rows x 128 K x 2B)
  __shared__ char sT[16384];       // 32 rows x 256 cols x 2B

  const int tid = threadIdx.x;
  const int lane = tid & 63;
  const int w = tid >> 6;           // 8 waves
  const int q = lane >> 4;
  const int l15 = lane & 15;
  const int b = blockIdx.x >> 1;
  const int half = blockIdx.x & 1;

  int n = nbuf[b];
  n = n < 0 ? 0 : (n > MAXN ? MAXN : n);   // defensive clamp
  int live = n - half * 32;                 // live rows in this block's 32-row slice
  live = live < 0 ? 0 : (live > 32 ? 32 : live);

  float* ob = out + (size_t)b * (MAXN * D_OUT) + (size_t)half * 32 * D_OUT;

  if (live == 0) {                  // dead slice: zero-fill 32x512 fp32 and exit
    const float4 z4f = make_float4(0.f, 0.f, 0.f, 0.f);
#pragma unroll
    for (int i = 0; i < 8; ++i) *(float4*)(ob + i * 2048 + tid * 4) = z4f;
    return;
  }
  const int JT = (live + 15) >> 4;  // live 16-row M-tiles (1 or 2), block-uniform

  // ---- A generation: 512 threads cover 32 rows x 128 K per stage (uint4 = 8 bf16 each)
  const int gj = tid >> 4;          // row 0..31
  const int gk = tid & 15;          // 16B chunk within 256B stage row
  const ushort_t* keyrow = key + (size_t)(half * 32 + gj) * H_SZ + gk * 8;
  const ushort_t* zrow = zc + (size_t)b * H_SZ + gk * 8;
  char* aw = sA + gj * 256 + ((gk ^ (gj & 7)) * 16);

  auto genA = [&](int s) {          // stage s covers k in [s*128, s*128+128)
    const int k0 = s * 128;
    uint4 kv = *(const uint4*)(keyrow + k0);
    uint4 zv = *(const uint4*)(zrow + k0);
    uint4 r;
    r.x = mul2bf(kv.x, zv.x); r.y = mul2bf(kv.y, zv.y);
    r.z = mul2bf(kv.z, zv.z); r.w = mul2bf(kv.w, zv.w);
    *(uint4*)(aw + (s & 1) * 8192) = r;
  };

  f32x4 z4 = {0.f, 0.f, 0.f, 0.f};
  f32x4 acc2[2][4];                 // X accumulator, persists across passes
#pragma unroll
  for (int mt = 0; mt < 2; ++mt)
#pragma unroll
    for (int i = 0; i < 4; ++i) acc2[mt][i] = z4;

  for (int p = 0; p < 3; ++p) {
    // ---- GEMM1 slab: T[:, p*256 .. p*256+256) ----
    f32x4 acc[2][2];
#pragma unroll
    for (int mt = 0; mt < 2; ++mt)
#pragma unroll
      for (int i = 0; i < 2; ++i) acc[mt][i] = z4;

    const ushort_t* bp1[2];
#pragma unroll
    for (int i = 0; i < 2; ++i)
      bp1[i] = w1t + (size_t)(p * 256 + (w * 2 + i) * 16 + l15) * H_SZ + q * 8;

    genA(0);
    __syncthreads();

    for (int s = 0; s < 8; ++s) {
      if (s < 7) genA(s + 1);
      const char* ab = sA + (s & 1) * 8192;
      const int kb = s * 128;
#pragma unroll
      for (int kk = 0; kk < 4; ++kk) {
        bf16x8 bfr[2];
#pragma unroll
        for (int i = 0; i < 2; ++i) bfr[i] = *(const bf16x8*)(bp1[i] + kb + kk * 32);
        bf16x8 afr[2];
#pragma unroll
        for (int mt = 0; mt < 2; ++mt)
          if (mt < JT)
            afr[mt] = *(const bf16x8*)(ab + (mt * 16 + l15) * 256 + (((kk * 4 + q) ^ (l15 & 7)) * 16));
#pragma unroll
        for (int mt = 0; mt < 2; ++mt)
          if (mt < JT)
#pragma unroll
            for (int i = 0; i < 2; ++i)
              acc[mt][i] = __builtin_amdgcn_mfma_f32_16x16x32_bf16(afr[mt], bfr[i], acc[mt][i], 0, 0, 0);
      }
      __syncthreads();
    }

    // ---- epilogue 1: +bias, mish, bf16 -> sT (XOR-swizzled 16B chunks) ----
#pragma unroll
    for (int mt = 0; mt < 2; ++mt)
      if (mt < JT)
#pragma unroll
        for (int i = 0; i < 2; ++i) {
          const int pl = (w * 2 + i) * 16 + l15;       // local col 0..255
          const float bias = db1[p * 256 + pl];
          const int c = pl >> 3;
          const int off = (pl & 7) * 2;
#pragma unroll
          for (int r = 0; r < 4; ++r) {
            const int j = mt * 16 + q * 4 + r;
            *(ushort_t*)(sT + j * 512 + ((c ^ (j & 7)) * 16 + off)) = f2bf(mish_f(acc[mt][i][r] + bias));
          }
        }
    __syncthreads();

    // ---- GEMM2 partial: acc2 += T-slab @ W2[k-slab, :] ----
    const ushort_t* bp2[4];
#pragma unroll
    for (int i = 0; i < 4; ++i)
      bp2[i] = w2t + (size_t)((w * 4 + i) * 16 + l15) * MIDDEC + p * 256 + q * 8;

    for (int ksl = 0; ksl < 8; ++ksl) {
      bf16x8 bfr[4];
#pragma unroll
      for (int i = 0; i < 4; ++i) bfr[i] = *(const bf16x8*)(bp2[i] + ksl * 32);
      bf16x8 afr[2];
#pragma unroll
      for (int mt = 0; mt < 2; ++mt)
        if (mt < JT) {
          const int j = mt * 16 + l15;
          const int c = ksl * 4 + q;
          afr[mt] = *(const bf16x8*)(sT + j * 512 + ((c ^ (j & 7)) * 16));
        }
#pragma unroll
      for (int mt = 0; mt < 2; ++mt)
        if (mt < JT)
#pragma unroll
          for (int i = 0; i < 4; ++i)
            acc2[mt][i] = __builtin_amdgcn_mfma_f32_16x16x32_bf16(afr[mt], bfr[i], acc2[mt][i], 0, 0, 0);
    }
    __syncthreads();   // sT reads done before next pass's epilogue overwrites
  }

  // ---- X epilogue + store, in 2 halves of 256 cols (sT holds one half) ----
  for (int h = 0; h < 2; ++h) {
    if ((w >> 2) == h) {             // waves owning cols [h*256, h*256+256)
#pragma unroll
      for (int mt = 0; mt < 2; ++mt)
        if (mt < JT)
#pragma unroll
          for (int i = 0; i < 4; ++i) {
            const int col = (w * 4 + i) * 16 + l15;    // global col
            const int cl = col & 255;
            const float bias = db2[col];
#pragma unroll
            for (int r = 0; r < 4; ++r) {
              const int j = mt * 16 + q * 4 + r;
              *(ushort_t*)(sT + j * 512 + cl * 2) = f2bf(acc2[mt][i][r] + bias);
            }
          }
    }
    __syncthreads();
    float* oh = ob + h * 256;
#pragma unroll
    for (int it = 0; it < 2; ++it) {
      const int e = it * 4096 + tid * 8;   // 0..8191 within 32x256 half
      const int row = e >> 8, cl = e & 255;
      float4 v0 = make_float4(0.f, 0.f, 0.f, 0.f);
      float4 v1 = make_float4(0.f, 0.f, 0.f, 0.f);
      if (row < live) {
        const uint4 u = *(const uint4*)(sT + row * 512 + cl * 2);
        v0.x = asf(u.x << 16); v0.y = asf(u.x & 0xffff0000u);
        v0.z = asf(u.y << 16); v0.w = asf(u.y & 0xffff0000u);
        v1.x = asf(u.z << 16); v1.y = asf(u.z & 0xffff0000u);
        v1.z = asf(u.w << 16); v1.w = asf(u.w & 0xffff0000u);
      }
      *(float4*)(oh + (size_t)row * D_OUT + cl) = v0;
      *(float4*)(oh + (size_t)row * D_OUT + cl + 4) = v1;
    }
    __syncthreads();   // store reads done before h=1 epilogue overwrites sT
  }
}

// ---------------- launcher ----------------
extern "C" void kernel_launch(void* const* d_in, const int* in_sizes, int n_in,
                              void* d_out, int out_size, void* d_ws, size_t ws_size,
                              hipStream_t stream) {
  const float* z      = (const float*)d_in[0];
  const float* key    = (const float*)d_in[1];
  const float* sp_w1  = (const float*)d_in[2];
  const float* sp_b1  = (const float*)d_in[3];
  const float* sp_g   = (const float*)d_in[4];
  const float* sp_be  = (const float*)d_in[5];
  const float* sp_w2  = (const float*)d_in[6];
  const float* sp_b2  = (const float*)d_in[7];
  const float* cd_w1  = (const float*)d_in[8];
  const float* cd_b1  = (const float*)d_in[9];
  const float* cd_w2  = (const float*)d_in[10];
  const float* cd_b2  = (const float*)d_in[11];
  const float* dec_w1 = (const float*)d_in[12];
  const float* dec_b1 = (const float*)d_in[13];
  const float* dec_w2 = (const float*)d_in[14];
  const float* dec_b2 = (const float*)d_in[15];

  char* ws = (char*)d_ws;
  float*    enc   = (float*)(ws + 0);           // 65*1024*4   = 266,240
  int*      nbuf  = (int*)(ws + 266240);        // 2048*4      = 8,192
  ushort_t* zc    = (ushort_t*)(ws + 274432);   // 2048*1024*2 = 4,194,304
  ushort_t* w1t   = (ushort_t*)(ws + 4468736);  // 768*1024*2  = 1,572,864
  ushort_t* w2t   = (ushort_t*)(ws + 6041600);  // 512*768*2   = 786,432
  ushort_t* keyb  = (ushort_t*)(ws + 6828032);  // 64*1024*2   = 131,072

  float* out  = (float*)d_out;                           // x: 2048*64*512 fp32
  float* outb = out + (size_t)2048 * MAXN * D_OUT;       // batch: 2048*64 fp32

  (void)in_sizes; (void)n_in; (void)out_size; (void)ws_size;

  k_transpose_cvt<<<dim3(768 / 32, 1024 / 32), 256, 0, stream>>>(dec_w1, w1t, 1024, 768);
  k_transpose_cvt<<<dim3(512 / 32, 768 / 32), 256, 0, stream>>>(dec_w2, w2t, 768, 512);
  k_cvtkey<<<64, 256, 0, stream>>>(key, keyb);
  k_enc<<<65, 256, 0, stream>>>(cd_w1, cd_b1, cd_w2, cd_b2, enc);
  k_npath<<<256, 256, 0, stream>>>(z, sp_w1, sp_b1, sp_g, sp_be, sp_w2, sp_b2, enc, nbuf, zc, outb);
  k_dec<<<4096, 512, 0, stream>>>(keyb, w1t, dec_b1, w2t, dec_b2, zc, nbuf, out);
}

// Round 4
// 1210.292 us; speedup vs baseline: 1.4213x; 1.4213x over previous
//
#include <hip/hip_runtime.h>
#include <stdint.h>

typedef unsigned short ushort_t;
typedef unsigned int uint_t;

#define H_SZ   1024
#define D_OUT  512
#define MAXN   64
#define MIDSP  512
#define MIDCD  512
#define MIDDEC 768

typedef __bf16 bf16x8 __attribute__((ext_vector_type(8)));
typedef float  f32x4  __attribute__((ext_vector_type(4)));

static __device__ __forceinline__ float asf(uint_t u) { union { uint_t i; float f; } c; c.i = u; return c.f; }
static __device__ __forceinline__ uint_t rnbf(float f) {            // fp32 -> bf16 (RNE), low 16 bits
  union { uint_t i; float f; } c; c.f = f;
  return (c.i + 0x7fffu + ((c.i >> 16) & 1u)) >> 16;
}
static __device__ __forceinline__ ushort_t f2bf(float f) { return (ushort_t)rnbf(f); }
static __device__ __forceinline__ uint_t mul2bf(uint_t a, uint_t b) {  // 2x packed bf16 multiply
  float a0 = asf(a << 16), a1 = asf(a & 0xffff0000u);
  float b0 = asf(b << 16), b1 = asf(b & 0xffff0000u);
  return rnbf(a0 * b0) | (rnbf(a1 * b1) << 16);
}
static __device__ __forceinline__ double mish_d(double x) { return x * tanh(log1p(exp(x))); }
static __device__ __forceinline__ float mish_f(float x) {
  // mish(x) = x*(t^2+2t)/(t^2+2t+2), t=e^x  (algebraic tanh(softplus))
  float t = __expf(x);
  float u = t * t + 2.f * t;
  float r = u / (u + 2.f);
  return (x > 30.f) ? x : x * r;
}

// ---------------- transpose + fp32->bf16 convert (dims multiples of 32) ----------------
__global__ __launch_bounds__(256) void k_transpose_cvt(const float* __restrict__ src,
                                                       ushort_t* __restrict__ dst, int R, int C) {
  __shared__ float tile[32][33];
  const int c0 = blockIdx.x * 32, r0 = blockIdx.y * 32;
  const int tc = threadIdx.x & 31, tr = threadIdx.x >> 5;
#pragma unroll
  for (int i = 0; i < 4; ++i) {
    const int r = tr + i * 8;
    tile[r][tc] = src[(size_t)(r0 + r) * C + (c0 + tc)];
  }
  __syncthreads();
#pragma unroll
  for (int i = 0; i < 4; ++i) {
    const int rr = tr + i * 8;
    dst[(size_t)(c0 + rr) * R + (r0 + tc)] = f2bf(tile[tc][rr]);
  }
}

// ---------------- key table fp32 -> bf16 ----------------
__global__ __launch_bounds__(256) void k_cvtkey(const float* __restrict__ src, ushort_t* __restrict__ dst) {
  const int i = blockIdx.x * 1024 + threadIdx.x;
#pragma unroll
  for (int j = 0; j < 4; ++j) dst[i + j * 256] = f2bf(src[i + j * 256]);
}

// ---------------- enc table: enc[v] = mish(v*cd_w1+cd_b1) @ cd_w2 + cd_b2 ----------------
__global__ __launch_bounds__(256) void k_enc(const float* __restrict__ w1, const float* __restrict__ b1,
                                             const float* __restrict__ w2, const float* __restrict__ b2,
                                             float* __restrict__ enc) {
  const int v = blockIdx.x, t = threadIdx.x;
  __shared__ float m[MIDCD];
  for (int i = t; i < MIDCD; i += 256) {
    double a = (double)v * (double)w1[i] + (double)b1[i];
    m[i] = (float)mish_d(a);
  }
  __syncthreads();
  for (int c = t; c < H_SZ; c += 256) {
    double s = (double)b2[c];
    for (int k = 0; k < MIDCD; ++k) s += (double)m[k] * (double)w2[(size_t)k * H_SZ + c];
    enc[(size_t)v * H_SZ + c] = (float)s;
  }
}

// ---------------- n-path: 8 rows per block; fp32 S accumulation, fp64 LN/mish/dot ----------------
__global__ __launch_bounds__(256) void k_npath(
    const float* __restrict__ z, const float* __restrict__ w1, const float* __restrict__ b1,
    const float* __restrict__ g, const float* __restrict__ be,
    const float* __restrict__ w2, const float* __restrict__ b2,
    const float* __restrict__ enc, int* __restrict__ nbuf,
    ushort_t* __restrict__ zc, float* __restrict__ outb) {
  const int t = threadIdx.x;
  const int r0 = blockIdx.x * 8;
  const int lane = t & 63, wv = t >> 6;
  __shared__ float zs[8][H_SZ];      // 32 KB
  __shared__ double wred[4];
  __shared__ int n8[8];

#pragma unroll
  for (int i = 0; i < 32; ++i) {
    const int idx = i * 256 + t;
    zs[idx >> 10][idx & 1023] = z[(size_t)r0 * H_SZ + idx];
  }
  __syncthreads();

  const int c0 = t, c1 = t + 256;
  float a0[8], a1[8];
#pragma unroll
  for (int r = 0; r < 8; ++r) { a0[r] = 0.f; a1[r] = 0.f; }

  for (int k = 0; k < H_SZ; k += 4) {
    float4 zr[8];
#pragma unroll
    for (int r = 0; r < 8; ++r) zr[r] = *(const float4*)&zs[r][k];
#pragma unroll
    for (int kk = 0; kk < 4; ++kk) {
      const float w0 = w1[(size_t)(k + kk) * MIDSP + c0];
      const float w1v = w1[(size_t)(k + kk) * MIDSP + c1];
#pragma unroll
      for (int r = 0; r < 8; ++r) {
        const float zk = ((const float*)&zr[r])[kk];
        a0[r] += zk * w0;
        a1[r] += zk * w1v;
      }
    }
  }

  auto block_sum = [&](double v) -> double {
#pragma unroll
    for (int off = 32; off > 0; off >>= 1) v += __shfl_down(v, off, 64);
    if (lane == 0) wred[wv] = v;
    __syncthreads();
    const double s = wred[0] + wred[1] + wred[2] + wred[3];
    __syncthreads();
    return s;
  };

  const double bia0 = (double)b1[c0], bia1 = (double)b1[c1];
  const double g0 = (double)g[c0], g1 = (double)g[c1];
  const double be0 = (double)be[c0], be1 = (double)be[c1];
  const double wv0 = (double)w2[c0], wv1 = (double)w2[c1];
  const double b2v = (double)b2[0];

  for (int r = 0; r < 8; ++r) {
    const double x0 = (double)a0[r] + bia0;
    const double x1 = (double)a1[r] + bia1;
    const double mu = block_sum(x0 + x1) * (1.0 / 512.0);
    const double varr = block_sum((x0 - mu) * (x0 - mu) + (x1 - mu) * (x1 - mu)) * (1.0 / 512.0);
    const double rs = 1.0 / sqrt(varr + 1e-5);
    const double h0 = mish_d((x0 - mu) * rs * g0 + be0);
    const double h1 = mish_d((x1 - mu) * rs * g1 + be1);
    const double logit = block_sum(h0 * wv0 + h1 * wv1) + b2v;
    if (t == 0) n8[r] = (int)fmin(64.0, fmax(0.0, rint(logit)));  // rint = half-to-even = np.round
  }
  __syncthreads();

  if (t < 8) nbuf[r0 + t] = n8[t];
#pragma unroll
  for (int i = 0; i < 2; ++i) {
    const int idx = i * 256 + t;
    const int r = idx >> 6, j = idx & 63;
    outb[(size_t)(r0 + r) * MAXN + j] = (j < n8[r]) ? (float)(r0 + r) : -1.0f;
  }
#pragma unroll
  for (int i = 0; i < 32; ++i) {
    const int idx = i * 256 + t;
    const int r = idx >> 10, c = idx & 1023;
    zc[(size_t)(r0 + r) * H_SZ + c] = f2bf(zs[r][c] - enc[(size_t)n8[r] * H_SZ + c]);
  }
}

// ---------------- fused decoder v5: A resident in LDS (128K) + 16K sT = 144 KiB ----------
// R3 post-mortem: v4 requested 160 KiB static LDS = EXACT gfx950 capacity -> bench never
// ran (prime suspect; 128 KiB is the max plain-HIP-proven point). v5 keeps the v4
// architecture (A generated once -> GEMM1's 32 K-steps barrier-free; barriers/block
// ~51 -> ~13-21) but shrinks sT to 32 rows x 256 cols by doing epilogue1+GEMM2 in two
// 32-row halves. When n<=32 (common: logits biased to 32) the second half is skipped
// (block-uniform). Per-mt accumulation order identical to v2 -> numerics inherited.
// 1 block/CU by design (R1/R2 proved the ~180-reg live set spills under any 128-reg cap).
__global__ __launch_bounds__(512, 2) void k_dec(
    const ushort_t* __restrict__ key, const ushort_t* __restrict__ w1t,
    const float* __restrict__ db1, const ushort_t* __restrict__ w2t,
    const float* __restrict__ db2, const ushort_t* __restrict__ zc,
    const int* __restrict__ nbuf, float* __restrict__ out) {
  __shared__ char sA[131072];      // 64 rows x 1024 K bf16, row stride 2048B, XOR-16B-chunk swizzle
  __shared__ char sT[16384];       // 32 rows x 256 cols bf16, row stride 512B, XOR swizzle

  const int tid = threadIdx.x;
  const int lane = tid & 63;
  const int w = tid >> 6;           // 8 waves
  const int q = lane >> 4;
  const int l15 = lane & 15;
  const int b = blockIdx.x;

  int n = nbuf[b];
  n = n < 0 ? 0 : (n > MAXN ? MAXN : n);   // defensive clamp
  float* ob = out + (size_t)b * (MAXN * D_OUT);

  if (n == 0) {                     // dead b: zero-fill 64x512 fp32 and exit (uniform)
    const float4 z4f = make_float4(0.f, 0.f, 0.f, 0.f);
#pragma unroll
    for (int i = 0; i < 16; ++i) *(float4*)(ob + i * 2048 + tid * 4) = z4f;
    return;
  }
  const int JT = (n + 15) >> 4;     // live 16-row M-tiles (1..4), block-uniform

  // ---- A generation, ONCE: row gj = tid>>3 (0..63), 16 chunks of 8 bf16 per thread ----
  {
    const int gj = tid >> 3;        // row 0..63
    const int gk = tid & 7;         // 16B chunk phase
    const ushort_t* keyrow = key + (size_t)gj * H_SZ + gk * 8;
    const ushort_t* zrow = zc + (size_t)b * H_SZ + gk * 8;
    char* awbase = sA + gj * 2048;
    const int xj = gj & 7;
#pragma unroll
    for (int i = 0; i < 16; ++i) {
      const int c = i * 8 + gk;     // chunk index 0..127 (XOR touches low 3 bits only)
      uint4 kv = *(const uint4*)(keyrow + i * 64);
      uint4 zv = *(const uint4*)(zrow + i * 64);
      uint4 r;
      r.x = mul2bf(kv.x, zv.x); r.y = mul2bf(kv.y, zv.y);
      r.z = mul2bf(kv.z, zv.z); r.w = mul2bf(kv.w, zv.w);
      *(uint4*)(awbase + ((c ^ xj) * 16)) = r;
    }
  }
  __syncthreads();

  f32x4 z4 = {0.f, 0.f, 0.f, 0.f};
  f32x4 acc2[4][4];                 // X accumulator, persists across passes
#pragma unroll
  for (int mt = 0; mt < 4; ++mt)
#pragma unroll
    for (int i = 0; i < 4; ++i) acc2[mt][i] = z4;

  for (int p = 0; p < 3; ++p) {
    // ---- GEMM1 slab: T[:, p*256 .. p*256+256), barrier-free over K=1024 ----
    f32x4 acc[4][2];
#pragma unroll
    for (int mt = 0; mt < 4; ++mt)
#pragma unroll
      for (int i = 0; i < 2; ++i) acc[mt][i] = z4;

    const ushort_t* bp1[2];
#pragma unroll
    for (int i = 0; i < 2; ++i)
      bp1[i] = w1t + (size_t)(p * 256 + (w * 2 + i) * 16 + l15) * H_SZ + q * 8;

#pragma unroll 4
    for (int ks = 0; ks < 32; ++ks) {      // k-offset = ks*32, same order as v2 (bitwise-equal)
      bf16x8 bfr[2];
#pragma unroll
      for (int i = 0; i < 2; ++i) bfr[i] = *(const bf16x8*)(bp1[i] + ks * 32);
      bf16x8 afr[4];
#pragma unroll
      for (int mt = 0; mt < 4; ++mt)
        if (mt < JT)
          afr[mt] = *(const bf16x8*)(sA + (mt * 16 + l15) * 2048 + (((ks * 4 + q) ^ (l15 & 7)) * 16));
#pragma unroll
      for (int mt = 0; mt < 4; ++mt)
        if (mt < JT)
#pragma unroll
          for (int i = 0; i < 2; ++i)
            acc[mt][i] = __builtin_amdgcn_mfma_f32_16x16x32_bf16(afr[mt], bfr[i], acc[mt][i], 0, 0, 0);
    }

    // ---- epilogue1 + GEMM2 in two 32-row halves (sT holds 32 rows) ----
    const ushort_t* bp2[4];
#pragma unroll
    for (int i = 0; i < 4; ++i)
      bp2[i] = w2t + (size_t)((w * 4 + i) * 16 + l15) * MIDDEC + p * 256 + q * 8;

    for (int rh = 0; rh < 2; ++rh) {
      if (rh * 2 >= JT) break;      // block-uniform: no live tiles in this half
      // epilogue1: +bias, mish, bf16 -> sT (XOR-swizzled 16B chunks), rows mt in {2rh, 2rh+1}
#pragma unroll
      for (int mloc = 0; mloc < 2; ++mloc) {
        const int mt = rh * 2 + mloc;
        if (mt < JT)
#pragma unroll
          for (int i = 0; i < 2; ++i) {
            const int pl = (w * 2 + i) * 16 + l15;       // local col 0..255
            const float bias = db1[p * 256 + pl];
            const int c = pl >> 3;
            const int off = (pl & 7) * 2;
#pragma unroll
            for (int r = 0; r < 4; ++r) {
              const int j = mloc * 16 + q * 4 + r;
              *(ushort_t*)(sT + j * 512 + ((c ^ (j & 7)) * 16 + off)) = f2bf(mish_f(acc[mt][i][r] + bias));
            }
          }
      }
      __syncthreads();

      // GEMM2 partial: acc2[2rh..2rh+1] += T-halfslab @ W2[k-slab, :]
      for (int ksl = 0; ksl < 8; ++ksl) {
        bf16x8 bfr[4];
#pragma unroll
        for (int i = 0; i < 4; ++i) bfr[i] = *(const bf16x8*)(bp2[i] + ksl * 32);
        bf16x8 afr[2];
#pragma unroll
        for (int mloc = 0; mloc < 2; ++mloc)
          if (rh * 2 + mloc < JT) {
            const int j = mloc * 16 + l15;
            const int c = ksl * 4 + q;
            afr[mloc] = *(const bf16x8*)(sT + j * 512 + ((c ^ (j & 7)) * 16));
          }
#pragma unroll
        for (int mloc = 0; mloc < 2; ++mloc) {
          const int mt = rh * 2 + mloc;
          if (mt < JT)
#pragma unroll
            for (int i = 0; i < 4; ++i)
              acc2[mt][i] = __builtin_amdgcn_mfma_f32_16x16x32_bf16(afr[mloc], bfr[i], acc2[mt][i], 0, 0, 0);
        }
      }
      __syncthreads();   // sT reads done before next half/pass epilogue overwrites
    }
  }

  // ---- X epilogue + store: (row-half rh) x (col-half h), 32x256 staged in sT ----
  for (int rh = 0; rh < 2; ++rh) {
    const int rbase = rh * 32;
    if (rbase < n) {
      const int lim = n - rbase;    // live rows in this half: 1..32
      for (int h = 0; h < 2; ++h) {
        if ((w >> 2) == h) {         // waves owning cols [h*256, h*256+256)
#pragma unroll
          for (int mloc = 0; mloc < 2; ++mloc) {
            const int mt = rh * 2 + mloc;
            if (mt < JT)
#pragma unroll
              for (int i = 0; i < 4; ++i) {
                const int col = (w * 4 + i) * 16 + l15;    // global col
                const int cl = col & 255;
                const float bias = db2[col];
#pragma unroll
                for (int r = 0; r < 4; ++r) {
                  const int j = mloc * 16 + q * 4 + r;
                  *(ushort_t*)(sT + j * 512 + cl * 2) = f2bf(acc2[mt][i][r] + bias);
                }
              }
          }
        }
        __syncthreads();
        float* oh = ob + (size_t)rbase * D_OUT + h * 256;
#pragma unroll
        for (int it = 0; it < 2; ++it) {
          const int e = it * 4096 + tid * 8;   // 0..8191 within 32x256 quarter
          const int row = e >> 8, cl = e & 255;
          float4 v0 = make_float4(0.f, 0.f, 0.f, 0.f);
          float4 v1 = make_float4(0.f, 0.f, 0.f, 0.f);
          if (row < lim) {
            const uint4 u = *(const uint4*)(sT + row * 512 + cl * 2);
            v0.x = asf(u.x << 16); v0.y = asf(u.x & 0xffff0000u);
            v0.z = asf(u.y << 16); v0.w = asf(u.y & 0xffff0000u);
            v1.x = asf(u.z << 16); v1.y = asf(u.z & 0xffff0000u);
            v1.z = asf(u.w << 16); v1.w = asf(u.w & 0xffff0000u);
          }
          *(float4*)(oh + (size_t)row * D_OUT + cl) = v0;
          *(float4*)(oh + (size_t)row * D_OUT + cl + 4) = v1;
        }
        __syncthreads();   // store reads done before next stage overwrites sT
      }
    } else {               // dead row-half: zero-fill 32x512 fp32 (no LDS, no barrier)
      float* oz = ob + (size_t)rbase * D_OUT;
      const float4 z4f = make_float4(0.f, 0.f, 0.f, 0.f);
#pragma unroll
      for (int i = 0; i < 8; ++i) *(float4*)(oz + i * 2048 + tid * 4) = z4f;
    }
  }
}

// ---------------- launcher ----------------
extern "C" void kernel_launch(void* const* d_in, const int* in_sizes, int n_in,
                              void* d_out, int out_size, void* d_ws, size_t ws_size,
                              hipStream_t stream) {
  const float* z      = (const float*)d_in[0];
  const float* key    = (const float*)d_in[1];
  const float* sp_w1  = (const float*)d_in[2];
  const float* sp_b1  = (const float*)d_in[3];
  const float* sp_g   = (const float*)d_in[4];
  const float* sp_be  = (const float*)d_in[5];
  const float* sp_w2  = (const float*)d_in[6];
  const float* sp_b2  = (const float*)d_in[7];
  const float* cd_w1  = (const float*)d_in[8];
  const float* cd_b1  = (const float*)d_in[9];
  const float* cd_w2  = (const float*)d_in[10];
  const float* cd_b2  = (const float*)d_in[11];
  const float* dec_w1 = (const float*)d_in[12];
  const float* dec_b1 = (const float*)d_in[13];
  const float* dec_w2 = (const float*)d_in[14];
  const float* dec_b2 = (const float*)d_in[15];

  char* ws = (char*)d_ws;
  float*    enc   = (float*)(ws + 0);           // 65*1024*4   = 266,240
  int*      nbuf  = (int*)(ws + 266240);        // 2048*4      = 8,192
  ushort_t* zc    = (ushort_t*)(ws + 274432);   // 2048*1024*2 = 4,194,304
  ushort_t* w1t   = (ushort_t*)(ws + 4468736);  // 768*1024*2  = 1,572,864
  ushort_t* w2t   = (ushort_t*)(ws + 6041600);  // 512*768*2   = 786,432
  ushort_t* keyb  = (ushort_t*)(ws + 6828032);  // 64*1024*2   = 131,072

  float* out  = (float*)d_out;                           // x: 2048*64*512 fp32
  float* outb = out + (size_t)2048 * MAXN * D_OUT;       // batch: 2048*64 fp32

  (void)in_sizes; (void)n_in; (void)out_size; (void)ws_size;

  k_transpose_cvt<<<dim3(768 / 32, 1024 / 32), 256, 0, stream>>>(dec_w1, w1t, 1024, 768);
  k_transpose_cvt<<<dim3(512 / 32, 768 / 32), 256, 0, stream>>>(dec_w2, w2t, 768, 512);
  k_cvtkey<<<64, 256, 0, stream>>>(key, keyb);
  k_enc<<<65, 256, 0, stream>>>(cd_w1, cd_b1, cd_w2, cd_b2, enc);
  k_npath<<<256, 256, 0, stream>>>(z, sp_w1, sp_b1, sp_g, sp_be, sp_w2, sp_b2, enc, nbuf, zc, outb);
  k_dec<<<2048, 512, 0, stream>>>(keyb, w1t, dec_b1, w2t, dec_b2, zc, nbuf, out);
}

// Round 5
// 1094.034 us; speedup vs baseline: 1.5723x; 1.1063x over previous
//
#include <hip/hip_runtime.h>
#include <stdint.h>

typedef unsigned short ushort_t;
typedef unsigned int uint_t;

#define H_SZ   1024
#define D_OUT  512
#define MAXN   64
#define MIDSP  512
#define MIDCD  512
#define MIDDEC 768

typedef __bf16 bf16x8 __attribute__((ext_vector_type(8)));
typedef float  f32x4  __attribute__((ext_vector_type(4)));

static __device__ __forceinline__ float asf(uint_t u) { union { uint_t i; float f; } c; c.i = u; return c.f; }
static __device__ __forceinline__ uint_t rnbf(float f) {            // fp32 -> bf16 (RNE), low 16 bits
  union { uint_t i; float f; } c; c.f = f;
  return (c.i + 0x7fffu + ((c.i >> 16) & 1u)) >> 16;
}
static __device__ __forceinline__ ushort_t f2bf(float f) { return (ushort_t)rnbf(f); }
static __device__ __forceinline__ uint_t mul2bf(uint_t a, uint_t b) {  // 2x packed bf16 multiply
  float a0 = asf(a << 16), a1 = asf(a & 0xffff0000u);
  float b0 = asf(b << 16), b1 = asf(b & 0xffff0000u);
  return rnbf(a0 * b0) | (rnbf(a1 * b1) << 16);
}
static __device__ __forceinline__ double mish_d(double x) { return x * tanh(log1p(exp(x))); }
static __device__ __forceinline__ float mish_f(float x) {
  // mish(x) = x*(t^2+2t)/(t^2+2t+2), t=e^x  (algebraic tanh(softplus))
  float t = __expf(x);
  float u = t * t + 2.f * t;
  float r = u / (u + 2.f);
  return (x > 30.f) ? x : x * r;
}

// ---------------- transpose + fp32->bf16 convert (dims multiples of 32) ----------------
__global__ __launch_bounds__(256) void k_transpose_cvt(const float* __restrict__ src,
                                                       ushort_t* __restrict__ dst, int R, int C) {
  __shared__ float tile[32][33];
  const int c0 = blockIdx.x * 32, r0 = blockIdx.y * 32;
  const int tc = threadIdx.x & 31, tr = threadIdx.x >> 5;
#pragma unroll
  for (int i = 0; i < 4; ++i) {
    const int r = tr + i * 8;
    tile[r][tc] = src[(size_t)(r0 + r) * C + (c0 + tc)];
  }
  __syncthreads();
#pragma unroll
  for (int i = 0; i < 4; ++i) {
    const int rr = tr + i * 8;
    dst[(size_t)(c0 + rr) * R + (r0 + tc)] = f2bf(tile[tc][rr]);
  }
}

// ---------------- key table fp32 -> bf16 ----------------
__global__ __launch_bounds__(256) void k_cvtkey(const float* __restrict__ src, ushort_t* __restrict__ dst) {
  const int i = blockIdx.x * 1024 + threadIdx.x;
#pragma unroll
  for (int j = 0; j < 4; ++j) dst[i + j * 256] = f2bf(src[i + j * 256]);
}

// ---------------- enc table: enc[v] = mish(v*cd_w1+cd_b1) @ cd_w2 + cd_b2 ----------------
// grid (65, 4): blockIdx.y picks a 256-col quarter -> 260 blocks (was 65 = 1/4 of CUs).
// Per-column accumulation order identical to before.
__global__ __launch_bounds__(256) void k_enc(const float* __restrict__ w1, const float* __restrict__ b1,
                                             const float* __restrict__ w2, const float* __restrict__ b2,
                                             float* __restrict__ enc) {
  const int v = blockIdx.x, t = threadIdx.x;
  const int c = blockIdx.y * 256 + t;
  __shared__ float m[MIDCD];
  for (int i = t; i < MIDCD; i += 256) {
    double a = (double)v * (double)w1[i] + (double)b1[i];
    m[i] = (float)mish_d(a);
  }
  __syncthreads();
  double s = (double)b2[c];
  for (int k = 0; k < MIDCD; ++k) s += (double)m[k] * (double)w2[(size_t)k * H_SZ + c];
  enc[(size_t)v * H_SZ + c] = (float)s;
}

// ---------------- n-path: 4 rows per block (grid 512 -> 2 blocks/CU for TLP) ----------------
// fp32 S accumulation, fp64 LN/mish/dot. Per-row numerics identical to the 8-row version.
__global__ __launch_bounds__(256) void k_npath(
    const float* __restrict__ z, const float* __restrict__ w1, const float* __restrict__ b1,
    const float* __restrict__ g, const float* __restrict__ be,
    const float* __restrict__ w2, const float* __restrict__ b2,
    const float* __restrict__ enc, int* __restrict__ nbuf,
    ushort_t* __restrict__ zc, float* __restrict__ outb) {
  const int t = threadIdx.x;
  const int r0 = blockIdx.x * 4;
  const int lane = t & 63, wv = t >> 6;
  __shared__ float zs[4][H_SZ];      // 16 KB
  __shared__ double wred[4];
  __shared__ int n4[4];

#pragma unroll
  for (int i = 0; i < 16; ++i) {
    const int idx = i * 256 + t;
    zs[idx >> 10][idx & 1023] = z[(size_t)r0 * H_SZ + idx];
  }
  __syncthreads();

  const int c0 = t, c1 = t + 256;
  float a0[4], a1[4];
#pragma unroll
  for (int r = 0; r < 4; ++r) { a0[r] = 0.f; a1[r] = 0.f; }

  for (int k = 0; k < H_SZ; k += 4) {
    float4 zr[4];
#pragma unroll
    for (int r = 0; r < 4; ++r) zr[r] = *(const float4*)&zs[r][k];
#pragma unroll
    for (int kk = 0; kk < 4; ++kk) {
      const float w0 = w1[(size_t)(k + kk) * MIDSP + c0];
      const float w1v = w1[(size_t)(k + kk) * MIDSP + c1];
#pragma unroll
      for (int r = 0; r < 4; ++r) {
        const float zk = ((const float*)&zr[r])[kk];
        a0[r] += zk * w0;
        a1[r] += zk * w1v;
      }
    }
  }

  auto block_sum = [&](double v) -> double {
#pragma unroll
    for (int off = 32; off > 0; off >>= 1) v += __shfl_down(v, off, 64);
    if (lane == 0) wred[wv] = v;
    __syncthreads();
    const double s = wred[0] + wred[1] + wred[2] + wred[3];
    __syncthreads();
    return s;
  };

  const double bia0 = (double)b1[c0], bia1 = (double)b1[c1];
  const double g0 = (double)g[c0], g1 = (double)g[c1];
  const double be0 = (double)be[c0], be1 = (double)be[c1];
  const double wv0 = (double)w2[c0], wv1 = (double)w2[c1];
  const double b2v = (double)b2[0];

  for (int r = 0; r < 4; ++r) {
    const double x0 = (double)a0[r] + bia0;
    const double x1 = (double)a1[r] + bia1;
    const double mu = block_sum(x0 + x1) * (1.0 / 512.0);
    const double varr = block_sum((x0 - mu) * (x0 - mu) + (x1 - mu) * (x1 - mu)) * (1.0 / 512.0);
    const double rs = 1.0 / sqrt(varr + 1e-5);
    const double h0 = mish_d((x0 - mu) * rs * g0 + be0);
    const double h1 = mish_d((x1 - mu) * rs * g1 + be1);
    const double logit = block_sum(h0 * wv0 + h1 * wv1) + b2v;
    if (t == 0) n4[r] = (int)fmin(64.0, fmax(0.0, rint(logit)));  // rint = half-to-even = np.round
  }
  __syncthreads();

  if (t < 4) nbuf[r0 + t] = n4[t];
  {
    const int r = t >> 6, j = t & 63;    // 256 = 4 rows x 64 cols
    outb[(size_t)(r0 + r) * MAXN + j] = (j < n4[r]) ? (float)(r0 + r) : -1.0f;
  }
#pragma unroll
  for (int i = 0; i < 16; ++i) {
    const int idx = i * 256 + t;
    const int r = idx >> 10, c = idx & 1023;
    zc[(size_t)(r0 + r) * H_SZ + c] = f2bf(zs[r][c] - enc[(size_t)n4[r] * H_SZ + c]);
  }
}

// ---------------- fused decoder v6: JT compile-time specialized, branch-free hot loops ----
// R4 post-mortem: barrier-free GEMM1 gained only 11%; counters show latency-bound
// (MfmaUtil 8.9 / VALU 14 / HBM 6 / occ 22 -- nothing saturated). Theory: runtime
// `if (mt < JT)` guards fragment the ks-loop into 4+ basic blocks per iteration,
// blocking load hoisting / waitcnt batching. v6 instantiates dec_core<JT> for JT=1..4
// (block-uniform switch). Hot path (n~32 for all b) is JT=2/3 with straight-line
// unrolled bodies and a smaller live accumulator set (acc2[2][4]=32 regs at JT=2).
// Numerics: identical accumulation order (only dead guarded ops removed).
template <int JT>
static __device__ __forceinline__ void dec_core(
    char* sA, char* sT,
    const ushort_t* __restrict__ w1t, const float* __restrict__ db1,
    const ushort_t* __restrict__ w2t, const float* __restrict__ db2,
    float* __restrict__ ob, const int tid, const int n) {
  const int lane = tid & 63;
  const int w = tid >> 6;           // 8 waves
  const int q = lane >> 4;
  const int l15 = lane & 15;
  constexpr int RH = (JT + 1) / 2;  // live 32-row halves (1 or 2)

  f32x4 z4 = {0.f, 0.f, 0.f, 0.f};
  f32x4 acc2[JT][4];                // X accumulator, persists across passes
#pragma unroll
  for (int mt = 0; mt < JT; ++mt)
#pragma unroll
    for (int i = 0; i < 4; ++i) acc2[mt][i] = z4;

  for (int p = 0; p < 3; ++p) {
    // ---- GEMM1 slab: T[:, p*256 .. p*256+256), barrier-free, branch-free over K=1024 ----
    f32x4 acc[JT][2];
#pragma unroll
    for (int mt = 0; mt < JT; ++mt)
#pragma unroll
      for (int i = 0; i < 2; ++i) acc[mt][i] = z4;

    const ushort_t* bp1[2];
#pragma unroll
    for (int i = 0; i < 2; ++i)
      bp1[i] = w1t + (size_t)(p * 256 + (w * 2 + i) * 16 + l15) * H_SZ + q * 8;

#pragma unroll 8
    for (int ks = 0; ks < 32; ++ks) {      // k-offset = ks*32, same order as v2/v5
      bf16x8 bfr0 = *(const bf16x8*)(bp1[0] + ks * 32);
      bf16x8 bfr1 = *(const bf16x8*)(bp1[1] + ks * 32);
      bf16x8 afr[JT];
#pragma unroll
      for (int mt = 0; mt < JT; ++mt)
        afr[mt] = *(const bf16x8*)(sA + (mt * 16 + l15) * 2048 + (((ks * 4 + q) ^ (l15 & 7)) * 16));
#pragma unroll
      for (int mt = 0; mt < JT; ++mt) {
        acc[mt][0] = __builtin_amdgcn_mfma_f32_16x16x32_bf16(afr[mt], bfr0, acc[mt][0], 0, 0, 0);
        acc[mt][1] = __builtin_amdgcn_mfma_f32_16x16x32_bf16(afr[mt], bfr1, acc[mt][1], 0, 0, 0);
      }
    }

    // ---- epilogue1 + GEMM2 in RH 32-row halves (sT holds 32 rows) ----
    const ushort_t* bp2[4];
#pragma unroll
    for (int i = 0; i < 4; ++i)
      bp2[i] = w2t + (size_t)((w * 4 + i) * 16 + l15) * MIDDEC + p * 256 + q * 8;

#pragma unroll
    for (int rh = 0; rh < RH; ++rh) {
      // epilogue1: +bias, mish, bf16 -> sT (XOR-swizzled 16B chunks), tiles {2rh, 2rh+1}
#pragma unroll
      for (int mloc = 0; mloc < 2; ++mloc) {
        if (rh * 2 + mloc < JT) {            // compile-time (rh, mloc constants)
          const int mt = rh * 2 + mloc;
#pragma unroll
          for (int i = 0; i < 2; ++i) {
            const int pl = (w * 2 + i) * 16 + l15;       // local col 0..255
            const float bias = db1[p * 256 + pl];
            const int c = pl >> 3;
            const int off = (pl & 7) * 2;
#pragma unroll
            for (int r = 0; r < 4; ++r) {
              const int j = mloc * 16 + q * 4 + r;
              *(ushort_t*)(sT + j * 512 + ((c ^ (j & 7)) * 16 + off)) = f2bf(mish_f(acc[mt][i][r] + bias));
            }
          }
        }
      }
      __syncthreads();

      // GEMM2 partial: acc2[2rh..2rh+1] += T-halfslab @ W2[k-slab, :]
#pragma unroll
      for (int ksl = 0; ksl < 8; ++ksl) {
        bf16x8 bfr[4];
#pragma unroll
        for (int i = 0; i < 4; ++i) bfr[i] = *(const bf16x8*)(bp2[i] + ksl * 32);
        bf16x8 afr2[2];
#pragma unroll
        for (int mloc = 0; mloc < 2; ++mloc)
          if (rh * 2 + mloc < JT) {
            const int j = mloc * 16 + l15;
            const int c = ksl * 4 + q;
            afr2[mloc] = *(const bf16x8*)(sT + j * 512 + ((c ^ (j & 7)) * 16));
          }
#pragma unroll
        for (int mloc = 0; mloc < 2; ++mloc) {
          if (rh * 2 + mloc < JT) {
            const int mt = rh * 2 + mloc;
#pragma unroll
            for (int i = 0; i < 4; ++i)
              acc2[mt][i] = __builtin_amdgcn_mfma_f32_16x16x32_bf16(afr2[mloc], bfr[i], acc2[mt][i], 0, 0, 0);
          }
        }
      }
      __syncthreads();   // sT reads done before next half/pass epilogue overwrites
    }
  }

  // ---- X epilogue + store: (row-half rh) x (col-half h), 32x256 staged in sT ----
#pragma unroll
  for (int rh = 0; rh < RH; ++rh) {
    const int rbase = rh * 32;
    const int lim0 = n - rbase;
    const int lim = lim0 > 32 ? 32 : lim0;   // live rows in this half: 1..32
    for (int h = 0; h < 2; ++h) {
      if ((w >> 2) == h) {         // waves owning cols [h*256, h*256+256)
#pragma unroll
        for (int mloc = 0; mloc < 2; ++mloc) {
          if (rh * 2 + mloc < JT) {
            const int mt = rh * 2 + mloc;
#pragma unroll
            for (int i = 0; i < 4; ++i) {
              const int col = (w * 4 + i) * 16 + l15;    // global col
              const int cl = col & 255;
              const float bias = db2[col];
#pragma unroll
              for (int r = 0; r < 4; ++r) {
                const int j = mloc * 16 + q * 4 + r;
                *(ushort_t*)(sT + j * 512 + cl * 2) = f2bf(acc2[mt][i][r] + bias);
              }
            }
          }
        }
      }
      __syncthreads();
      float* oh = ob + (size_t)rbase * D_OUT + h * 256;
#pragma unroll
      for (int it = 0; it < 2; ++it) {
        const int e = it * 4096 + tid * 8;   // 0..8191 within 32x256 quarter
        const int row = e >> 8, cl = e & 255;
        float4 v0 = make_float4(0.f, 0.f, 0.f, 0.f);
        float4 v1 = make_float4(0.f, 0.f, 0.f, 0.f);
        if (row < lim) {
          const uint4 u = *(const uint4*)(sT + row * 512 + cl * 2);
          v0.x = asf(u.x << 16); v0.y = asf(u.x & 0xffff0000u);
          v0.z = asf(u.y << 16); v0.w = asf(u.y & 0xffff0000u);
          v1.x = asf(u.z << 16); v1.y = asf(u.z & 0xffff0000u);
          v1.z = asf(u.w << 16); v1.w = asf(u.w & 0xffff0000u);
        }
        *(float4*)(oh + (size_t)row * D_OUT + cl) = v0;
        *(float4*)(oh + (size_t)row * D_OUT + cl + 4) = v1;
      }
      __syncthreads();   // store reads done before next stage overwrites sT
    }
  }
  if (RH == 1) {         // rows 32..63 dead for this b: zero-fill 32x512 fp32
    float* oz = ob + 32 * D_OUT;
    const float4 z4f = make_float4(0.f, 0.f, 0.f, 0.f);
#pragma unroll
    for (int i = 0; i < 8; ++i) *(float4*)(oz + i * 2048 + tid * 4) = z4f;
  }
}

__global__ __launch_bounds__(512, 2) void k_dec(
    const ushort_t* __restrict__ key, const ushort_t* __restrict__ w1t,
    const float* __restrict__ db1, const ushort_t* __restrict__ w2t,
    const float* __restrict__ db2, const ushort_t* __restrict__ zc,
    const int* __restrict__ nbuf, float* __restrict__ out) {
  __shared__ char sA[131072];      // 64 rows x 1024 K bf16, row stride 2048B, XOR-16B-chunk swizzle
  __shared__ char sT[16384];       // 32 rows x 256 cols bf16, row stride 512B, XOR swizzle

  const int tid = threadIdx.x;
  const int b = blockIdx.x;

  int n = nbuf[b];
  n = n < 0 ? 0 : (n > MAXN ? MAXN : n);   // defensive clamp
  float* ob = out + (size_t)b * (MAXN * D_OUT);

  if (n == 0) {                     // dead b: zero-fill 64x512 fp32 and exit (uniform)
    const float4 z4f = make_float4(0.f, 0.f, 0.f, 0.f);
#pragma unroll
    for (int i = 0; i < 16; ++i) *(float4*)(ob + i * 2048 + tid * 4) = z4f;
    return;
  }
  const int JT = (n + 15) >> 4;     // live 16-row M-tiles (1..4), block-uniform

  // ---- A generation, ONCE: row gj = tid>>3 (0..63), 16 chunks of 8 bf16 per thread ----
  {
    const int gj = tid >> 3;        // row 0..63
    const int gk = tid & 7;         // 16B chunk phase
    const ushort_t* keyrow = key + (size_t)gj * H_SZ + gk * 8;
    const ushort_t* zrow = zc + (size_t)b * H_SZ + gk * 8;
    char* awbase = sA + gj * 2048;
    const int xj = gj & 7;
#pragma unroll
    for (int i = 0; i < 16; ++i) {
      const int c = i * 8 + gk;     // chunk index 0..127 (XOR touches low 3 bits only)
      uint4 kv = *(const uint4*)(keyrow + i * 64);
      uint4 zv = *(const uint4*)(zrow + i * 64);
      uint4 r;
      r.x = mul2bf(kv.x, zv.x); r.y = mul2bf(kv.y, zv.y);
      r.z = mul2bf(kv.z, zv.z); r.w = mul2bf(kv.w, zv.w);
      *(uint4*)(awbase + ((c ^ xj) * 16)) = r;
    }
  }
  __syncthreads();

  switch (JT) {                     // block-uniform -> barriers inside are safe
    case 1:  dec_core<1>(sA, sT, w1t, db1, w2t, db2, ob, tid, n); break;
    case 2:  dec_core<2>(sA, sT, w1t, db1, w2t, db2, ob, tid, n); break;
    case 3:  dec_core<3>(sA, sT, w1t, db1, w2t, db2, ob, tid, n); break;
    default: dec_core<4>(sA, sT, w1t, db1, w2t, db2, ob, tid, n); break;
  }
}

// ---------------- launcher ----------------
extern "C" void kernel_launch(void* const* d_in, const int* in_sizes, int n_in,
                              void* d_out, int out_size, void* d_ws, size_t ws_size,
                              hipStream_t stream) {
  const float* z      = (const float*)d_in[0];
  const float* key    = (const float*)d_in[1];
  const float* sp_w1  = (const float*)d_in[2];
  const float* sp_b1  = (const float*)d_in[3];
  const float* sp_g   = (const float*)d_in[4];
  const float* sp_be  = (const float*)d_in[5];
  const float* sp_w2  = (const float*)d_in[6];
  const float* sp_b2  = (const float*)d_in[7];
  const float* cd_w1  = (const float*)d_in[8];
  const float* cd_b1  = (const float*)d_in[9];
  const float* cd_w2  = (const float*)d_in[10];
  const float* cd_b2  = (const float*)d_in[11];
  const float* dec_w1 = (const float*)d_in[12];
  const float* dec_b1 = (const float*)d_in[13];
  const float* dec_w2 = (const float*)d_in[14];
  const float* dec_b2 = (const float*)d_in[15];

  char* ws = (char*)d_ws;
  float*    enc   = (float*)(ws + 0);           // 65*1024*4   = 266,240
  int*      nbuf  = (int*)(ws + 266240);        // 2048*4      = 8,192
  ushort_t* zc    = (ushort_t*)(ws + 274432);   // 2048*1024*2 = 4,194,304
  ushort_t* w1t   = (ushort_t*)(ws + 4468736);  // 768*1024*2  = 1,572,864
  ushort_t* w2t   = (ushort_t*)(ws + 6041600);  // 512*768*2   = 786,432
  ushort_t* keyb  = (ushort_t*)(ws + 6828032);  // 64*1024*2   = 131,072

  float* out  = (float*)d_out;                           // x: 2048*64*512 fp32
  float* outb = out + (size_t)2048 * MAXN * D_OUT;       // batch: 2048*64 fp32

  (void)in_sizes; (void)n_in; (void)out_size; (void)ws_size;

  k_transpose_cvt<<<dim3(768 / 32, 1024 / 32), 256, 0, stream>>>(dec_w1, w1t, 1024, 768);
  k_transpose_cvt<<<dim3(512 / 32, 768 / 32), 256, 0, stream>>>(dec_w2, w2t, 768, 512);
  k_cvtkey<<<64, 256, 0, stream>>>(key, keyb);
  k_enc<<<dim3(65, 4), 256, 0, stream>>>(cd_w1, cd_b1, cd_w2, cd_b2, enc);
  k_npath<<<512, 256, 0, stream>>>(z, sp_w1, sp_b1, sp_g, sp_be, sp_w2, sp_b2, enc, nbuf, zc, outb);
  k_dec<<<2048, 512, 0, stream>>>(keyb, w1t, dec_b1, w2t, dec_b2, zc, nbuf, out);
}